// Round 10
// baseline (185.753 us; speedup 1.0000x reference)
//
#include <hip/hip_runtime.h>
#include <hip/hip_bf16.h>

// Switch MoE (top-1), B=2 S=1024 H=768 F=3072 E=8 on MI355X.
// Outputs concat in d_out: next_states[2048*768] f32, router_logits[2048*8] f32,
// expert_index[2048] written as float values.

#define T_TOKENS 2048
#define H_DIM 768
#define F_DIM 3072
#define E_NUM 8
#define MSLOTS 40  // 64-row tiles: sum ceil(cnt/64) <= 32+7, padded to 40

typedef __attribute__((ext_vector_type(8))) short bf16x8;
typedef __attribute__((ext_vector_type(4))) float f32x4;

__device__ inline unsigned short f2bf(float f) {
  __hip_bfloat16 b = __float2bfloat16(f);
  return *reinterpret_cast<unsigned short*>(&b);
}
__device__ inline unsigned int pack2(float lo, float hi) {
  return (unsigned int)f2bf(lo) | ((unsigned int)f2bf(hi) << 16);
}
__device__ inline float bf2f(unsigned short u) {
  unsigned int x = ((unsigned int)u) << 16;
  union { unsigned int i; float f; } c; c.i = x; return c.f;
}

// ---------------- Router: one wave per token ----------------
__global__ void router_kernel(const float* __restrict__ X, const float* __restrict__ Wr,
                              float* __restrict__ logits, float* __restrict__ idx_out,
                              int* __restrict__ expert, float* __restrict__ prob,
                              int* __restrict__ counts) {
  int wave = threadIdx.x >> 6, lane = threadIdx.x & 63;
  int t = blockIdx.x * 4 + wave;
  if (t >= T_TOKENS) return;
  const float* x = X + (size_t)t * H_DIM;
  float acc[E_NUM];
#pragma unroll
  for (int e = 0; e < E_NUM; ++e) acc[e] = 0.f;
  int h0 = lane * 12;
#pragma unroll
  for (int j = 0; j < 12; ++j) {
    float xv = x[h0 + j];
    const float4* wr = reinterpret_cast<const float4*>(Wr + (size_t)(h0 + j) * E_NUM);
    float4 w0 = wr[0], w1 = wr[1];
    acc[0] += xv * w0.x; acc[1] += xv * w0.y; acc[2] += xv * w0.z; acc[3] += xv * w0.w;
    acc[4] += xv * w1.x; acc[5] += xv * w1.y; acc[6] += xv * w1.z; acc[7] += xv * w1.w;
  }
#pragma unroll
  for (int e = 0; e < E_NUM; ++e) {
#pragma unroll
    for (int s = 32; s > 0; s >>= 1) acc[e] += __shfl_down(acc[e], s);
  }
  if (lane == 0) {
    float m = acc[0]; int am = 0;
#pragma unroll
    for (int e = 1; e < E_NUM; ++e) {
      if (acc[e] > m) { m = acc[e]; am = e; }  // strict > == jnp.argmax first-occurrence
    }
    float sum = 0.f;
#pragma unroll
    for (int e = 0; e < E_NUM; ++e) sum += __expf(acc[e] - m);
    float p = 1.f / sum;
#pragma unroll
    for (int e = 0; e < E_NUM; ++e) logits[(size_t)t * E_NUM + e] = acc[e];
    idx_out[t] = (float)am;
    expert[t] = am;
    prob[t] = p;
    atomicAdd(&counts[am], 1);
  }
}

// ------- Fused scan + scatter + slot table (one block) -------
__global__ void scan_scatter_kernel(const int* __restrict__ counts,
                                    const int* __restrict__ expert,
                                    int* __restrict__ offs, int* __restrict__ perm,
                                    int* __restrict__ mse, int* __restrict__ msm0) {
  __shared__ int so[E_NUM + 1];
  __shared__ int cur[E_NUM];
  int tid = threadIdx.x;
  if (tid == 0) {
    int s = 0;
    for (int e = 0; e < E_NUM; ++e) { so[e] = s; s += counts[e]; }
    so[E_NUM] = s;
    int ns = 0;
    for (int e = 0; e < E_NUM; ++e)
      for (int m0 = 0; m0 < counts[e]; m0 += 64) { mse[ns] = e; msm0[ns] = m0; ++ns; }
    for (; ns < MSLOTS; ++ns) { mse[ns] = -1; msm0[ns] = 0; }
  }
  if (tid < E_NUM) cur[tid] = 0;
  __syncthreads();
  if (tid < E_NUM + 1) offs[tid] = so[tid];
  for (int i = tid; i < T_TOKENS; i += blockDim.x) {
    int e = expert[i];
    int pos = atomicAdd(&cur[e], 1);
    perm[so[e] + pos] = i;
  }
}

// ------- Grouped GEMM: 64x64x64 tile, reg depth-3, 4 blocks/CU -------
// C[m,n] (+k-chunk) = sum_{k in chunk} A[m,k] * W[e][k,n]. BM=BN=BK=64,
// chunk 768 (nt=12). 4 waves 2m x 2n, wavetile 32x32 (acc 2x2).
// Double-buffered 32KB LDS + TWO register staging sets: tile t+1's loads are
// issued 2 full steps before its ds_write -> vmcnt wait fully covered.
// LDS rows 128B = 8 x 16B slots. A: physical slot = sp^(row&7), source linear.
// B: 4n x 4k per thread, b64 writes at slot=(kg>>1)^h(r), half=kg&1, where
// h(r) = (r&7)^((r>>3)&7). All write/read patterns enumerated bank-uniform.
// MODE 1: A = X f32 gathered via perm, out relu->bf16.
// MODE 0: A = bf16 linear (hbuf), out bf16 partials (split-K).
template <int MODE, int KT, int N, int KS>
__global__ __launch_bounds__(256, 4) void moe_gemm(
    const __hip_bfloat16* __restrict__ Abf, const float* __restrict__ Xf,
    const float* __restrict__ Wt,
    __hip_bfloat16* __restrict__ Cbf,
    const int* __restrict__ offs, const int* __restrict__ perm,
    const int* __restrict__ mse, const int* __restrict__ msm0) {
  constexpr int ABUF = 64 * 128;           // 8 KB
  constexpr int BUFSZ = ABUF + 64 * 128;   // 16 KB
  __shared__ __align__(16) char lds[2 * BUFSZ];  // 32 KB

  // ---- work decode with XCD-chunk swizzle (grid multiple of 8) ----
  const int nw = gridDim.x;
  const int cpx = nw >> 3;
  const int d = blockIdx.x;
  const int w = (d & 7) * cpx + (d >> 3);
  const int slot = w % MSLOTS;
  const int r_ = w / MSLOTS;
  const int ks = r_ % KS;
  const int nt_i = r_ / KS;
  const int e = mse[slot];
  if (e < 0) return;
  const int base = offs[e], cnt = offs[e + 1] - base;
  const int m0 = msm0[slot];
  const int rows = min(64, cnt - m0);
  const int n0 = nt_i * 64;
  const int koff = ks * 768;

  const int tid = threadIdx.x;
  const int lane = tid & 63, wv = tid >> 6;
  const int wr = wv >> 1, wc = wv & 1;     // 2m x 2n waves, wavetile 32x32
  const int lr = lane & 15, lg = lane >> 4;

  // ---- A staging: row=tid>>2, two 16B slots; linear source, swizzled write ----
  const int arow = tid >> 2, sp0 = (tid & 3) * 2, sp1 = sp0 + 1;
  const int arl = min(arow, rows - 1);
  const float* Ax0 = nullptr;
  const __hip_bfloat16* Ab0 = nullptr;
  if constexpr (MODE) {
    Ax0 = Xf + (size_t)perm[base + m0 + arl] * KT + sp0 * 8;
  } else {
    Ab0 = Abf + (size_t)(base + m0 + arl) * KT + koff + sp0 * 8;
  }
  const int a_woff0 = arow * 128 + ((sp0 ^ (arow & 7)) << 4);
  const int a_woff1 = arow * 128 + ((sp1 ^ (arow & 7)) << 4);

  // ---- B staging: 4 n-cols x 4 k-rows per thread, f32x4 loads, b64 writes ----
  const int n4 = (tid & 15) * 4;
  const int kg = tid >> 4;                 // 0..15, k = kg*4 .. kg*4+3
  const float* Bp = Wt + (size_t)e * KT * N + (size_t)(koff + kg * 4) * N + n0 + n4;
  int b_woff[4];
#pragma unroll
  for (int cc = 0; cc < 4; ++cc) {
    int rr = n4 + cc;
    int h_ = (rr & 7) ^ ((rr >> 3) & 7);
    b_woff[cc] = ABUF + rr * 128 + ((((kg >> 1) ^ h_) << 4) | ((kg & 1) << 3));
  }

  // ---- fragment LDS offsets ----
  int aof[2][2], bof[2][2];
#pragma unroll
  for (int k2 = 0; k2 < 2; ++k2) {
#pragma unroll
    for (int mi = 0; mi < 2; ++mi) {
      int ar = wr * 32 + mi * 16 + lr;
      aof[k2][mi] = ar * 128 + (((k2 * 4 + lg) ^ (ar & 7)) << 4);
    }
#pragma unroll
    for (int ni = 0; ni < 2; ++ni) {
      int br = wc * 32 + ni * 16 + lr;
      bof[k2][ni] = ABUF + br * 128 +
                    (((k2 * 4 + lg) ^ (br & 7) ^ ((br >> 3) & 7)) << 4);
    }
  }

  f32x4 acc[2][2];
#pragma unroll
  for (int i = 0; i < 2; ++i)
#pragma unroll
    for (int j = 0; j < 2; ++j) acc[i][j] = (f32x4){0.f, 0.f, 0.f, 0.f};

  // two register staging sets (depth-3)
  f32x4 afA[4], afB[4];
  int4 aqA[2], aqB[2];
  f32x4 bqA[4], bqB[4];

#define LOADT(S, TT) {                                                          \
    if constexpr (MODE) {                                                       \
      af##S[0] = *reinterpret_cast<const f32x4*>(Ax0 + (TT) * 64);              \
      af##S[1] = *reinterpret_cast<const f32x4*>(Ax0 + (TT) * 64 + 4);          \
      af##S[2] = *reinterpret_cast<const f32x4*>(Ax0 + (TT) * 64 + 8);          \
      af##S[3] = *reinterpret_cast<const f32x4*>(Ax0 + (TT) * 64 + 12);         \
    } else {                                                                    \
      aq##S[0] = *reinterpret_cast<const int4*>(Ab0 + (TT) * 64);               \
      aq##S[1] = *reinterpret_cast<const int4*>(Ab0 + (TT) * 64 + 8);           \
    }                                                                           \
    _Pragma("unroll")                                                           \
    for (int j = 0; j < 4; ++j)                                                 \
      bq##S[j] = *reinterpret_cast<const f32x4*>(Bp + (size_t)((TT) * 64 + j) * N); \
  }

#define WRITET(S, WB) {                                                         \
    char* wb_ = (WB);                                                           \
    if constexpr (MODE) {                                                       \
      int4 ua_;                                                                 \
      ua_.x = (int)pack2(af##S[0][0], af##S[0][1]);                             \
      ua_.y = (int)pack2(af##S[0][2], af##S[0][3]);                             \
      ua_.z = (int)pack2(af##S[1][0], af##S[1][1]);                             \
      ua_.w = (int)pack2(af##S[1][2], af##S[1][3]);                             \
      *reinterpret_cast<int4*>(wb_ + a_woff0) = ua_;                            \
      ua_.x = (int)pack2(af##S[2][0], af##S[2][1]);                             \
      ua_.y = (int)pack2(af##S[2][2], af##S[2][3]);                             \
      ua_.z = (int)pack2(af##S[3][0], af##S[3][1]);                             \
      ua_.w = (int)pack2(af##S[3][2], af##S[3][3]);                             \
      *reinterpret_cast<int4*>(wb_ + a_woff1) = ua_;                            \
    } else {                                                                    \
      *reinterpret_cast<int4*>(wb_ + a_woff0) = aq##S[0];                       \
      *reinterpret_cast<int4*>(wb_ + a_woff1) = aq##S[1];                       \
    }                                                                           \
    _Pragma("unroll")                                                           \
    for (int cc = 0; cc < 4; ++cc) {                                            \
      int2 u_;                                                                  \
      u_.x = (int)pack2(bq##S[0][cc], bq##S[1][cc]);                            \
      u_.y = (int)pack2(bq##S[2][cc], bq##S[3][cc]);                            \
      *reinterpret_cast<int2*>(wb_ + b_woff[cc]) = u_;                          \
    }                                                                           \
  }

#define MFMA_STEP(RB) {                                                         \
    const char* rb_ = (RB);                                                     \
    _Pragma("unroll")                                                           \
    for (int k2 = 0; k2 < 2; ++k2) {                                            \
      bf16x8 av0 = *reinterpret_cast<const bf16x8*>(rb_ + aof[k2][0]);          \
      bf16x8 av1 = *reinterpret_cast<const bf16x8*>(rb_ + aof[k2][1]);          \
      bf16x8 bv0 = *reinterpret_cast<const bf16x8*>(rb_ + bof[k2][0]);          \
      bf16x8 bv1 = *reinterpret_cast<const bf16x8*>(rb_ + bof[k2][1]);          \
      acc[0][0] = __builtin_amdgcn_mfma_f32_16x16x32_bf16(av0, bv0, acc[0][0], 0, 0, 0); \
      acc[0][1] = __builtin_amdgcn_mfma_f32_16x16x32_bf16(av0, bv1, acc[0][1], 0, 0, 0); \
      acc[1][0] = __builtin_amdgcn_mfma_f32_16x16x32_bf16(av1, bv0, acc[1][0], 0, 0, 0); \
      acc[1][1] = __builtin_amdgcn_mfma_f32_16x16x32_bf16(av1, bv1, acc[1][1], 0, 0, 0); \
    }                                                                           \
  }

#define SYNCB() {                                                               \
    asm volatile("s_waitcnt lgkmcnt(0)" ::: "memory");                          \
    __builtin_amdgcn_s_barrier();                                               \
    __builtin_amdgcn_sched_barrier(0);                                          \
  }

  char* const buf0 = lds;
  char* const buf1 = lds + BUFSZ;

  // prologue: tiles 0,1,2 in flight; tile0 -> buf0
  LOADT(A, 0);
  LOADT(B, 1);
  WRITET(A, buf0);   // counted vmcnt: tile1+tile2 loads stay outstanding
  LOADT(A, 2);
  SYNCB();

  // step t: MFMA buf[t&1]; write tile t+1 (loads issued 2 steps ago);
  // load tile t+3 into the just-freed register set. nt = 12.
#pragma unroll 1
  for (int t0 = 0; t0 < 8; t0 += 2) {
    MFMA_STEP(buf0); WRITET(B, buf1); LOADT(B, t0 + 3); SYNCB();
    MFMA_STEP(buf1); WRITET(A, buf0); LOADT(A, t0 + 4); SYNCB();
  }
  MFMA_STEP(buf0); WRITET(B, buf1); LOADT(B, 11); SYNCB();  // t=8
  MFMA_STEP(buf1); WRITET(A, buf0); SYNCB();                // t=9  (tile10)
  MFMA_STEP(buf0); WRITET(B, buf1); SYNCB();                // t=10 (tile11)
  MFMA_STEP(buf1);                                          // t=11
#undef LOADT
#undef WRITET
#undef MFMA_STEP
#undef SYNCB

  // ---- epilogue: C/D frag row=(lane>>4)*4+reg, col=lane&15 ----
#pragma unroll
  for (int mi = 0; mi < 2; ++mi) {
#pragma unroll
    for (int r = 0; r < 4; ++r) {
      int row = wr * 32 + mi * 16 + lg * 4 + r;
      if (row < rows) {
        if (MODE) {
          __hip_bfloat16* dst = Cbf + (size_t)(base + m0 + row) * N + n0 + wc * 32 + lr;
#pragma unroll
          for (int ni = 0; ni < 2; ++ni) {
            float v = acc[mi][ni][r];
            dst[ni * 16] = __float2bfloat16(v > 0.f ? v : 0.f);
          }
        } else {
          __hip_bfloat16* dst =
              Cbf + ((size_t)ks * T_TOKENS + base + m0 + row) * N + n0 + wc * 32 + lr;
#pragma unroll
          for (int ni = 0; ni < 2; ++ni)
            dst[ni * 16] = __float2bfloat16(acc[mi][ni][r]);
        }
      }
    }
  }
}

// -------- Split-K reduce: sum 4 bf16 partials, scale by prob, scatter --------
__global__ void reduce_kernel(const __hip_bfloat16* __restrict__ pc,
                              const int* __restrict__ perm,
                              const float* __restrict__ prob, float* __restrict__ out) {
  int idx = blockIdx.x * 256 + threadIdx.x;      // 2048 * 192
  int g = idx / (H_DIM / 4);
  int c4 = (idx - g * (H_DIM / 4)) * 4;
  int token = perm[g];
  float p = prob[token];
  float s0 = 0.f, s1 = 0.f, s2 = 0.f, s3 = 0.f;
#pragma unroll
  for (int ks = 0; ks < 4; ++ks) {
    ushort4 u = *reinterpret_cast<const ushort4*>(
        pc + ((size_t)ks * T_TOKENS + g) * H_DIM + c4);
    s0 += bf2f(u.x); s1 += bf2f(u.y); s2 += bf2f(u.z); s3 += bf2f(u.w);
  }
  f32x4 v = (f32x4){s0 * p, s1 * p, s2 * p, s3 * p};
  *reinterpret_cast<f32x4*>(out + (size_t)token * H_DIM + c4) = v;
}

extern "C" void kernel_launch(void* const* d_in, const int* in_sizes, int n_in,
                              void* d_out, int out_size, void* d_ws, size_t ws_size,
                              hipStream_t stream) {
  const float* X = (const float*)d_in[0];
  const float* Wr = (const float*)d_in[1];
  const float* W1 = (const float*)d_in[2];
  const float* W2 = (const float*)d_in[3];

  float* out_states = (float*)d_out;
  float* out_logits = out_states + (size_t)T_TOKENS * H_DIM;
  float* out_index = out_logits + (size_t)T_TOKENS * E_NUM;

  char* ws = (char*)d_ws;
  int* counts = (int*)(ws + 0);        // 8 ints
  int* offs = (int*)(ws + 64);         // 9 ints
  int* expert = (int*)(ws + 128);      // 2048 ints
  float* prob = (float*)(ws + 8320);   // 2048 f32
  int* perm = (int*)(ws + 16512);      // 2048 ints
  int* mse = (int*)(ws + 24704);       // 40 ints
  int* msm0 = (int*)(ws + 24896);      // 40 ints
  __hip_bfloat16* hbuf = (__hip_bfloat16*)(ws + 3171456);   // 2048*3072 bf16
  __hip_bfloat16* pc = (__hip_bfloat16*)(ws + 15754368);    // 4*2048*768 bf16

  hipMemsetAsync(d_ws, 0, 64, stream);  // zero counts

  router_kernel<<<T_TOKENS / 4, 256, 0, stream>>>(X, Wr, out_logits, out_index, expert, prob, counts);
  scan_scatter_kernel<<<1, 1024, 0, stream>>>(counts, expert, offs, perm, mse, msm0);

  // h = relu(gather(X) @ W1[e]) : K=768, N=3072 -> 48 x 40 = 1920 blocks
  moe_gemm<1, H_DIM, F_DIM, 1><<<(F_DIM / 64) * MSLOTS, 256, 0, stream>>>(
      nullptr, X, W1, hbuf, offs, perm, mse, msm0);
  // partial y_ks = h @ W2[e][ks-chunk] : 4 chunks of 768 -> 12 x 4 x 40 = 1920 blocks
  moe_gemm<0, F_DIM, H_DIM, 4><<<(H_DIM / 64) * 4 * MSLOTS, 256, 0, stream>>>(
      hbuf, nullptr, W2, pc, offs, perm, mse, msm0);
  // out[token] = prob * sum_ks pc[ks][g]
  reduce_kernel<<<(T_TOKENS * (H_DIM / 4)) / 256, 256, 0, stream>>>(pc, perm, prob, out_states);
}

// Round 11
// 157.375 us; speedup vs baseline: 1.1803x; 1.1803x over previous
//
#include <hip/hip_runtime.h>
#include <hip/hip_bf16.h>

// Switch MoE (top-1), B=2 S=1024 H=768 F=3072 E=8 on MI355X.
// Outputs concat in d_out: next_states[2048*768] f32, router_logits[2048*8] f32,
// expert_index[2048] written as float values.

#define T_TOKENS 2048
#define H_DIM 768
#define F_DIM 3072
#define E_NUM 8
#define MSLOTS 40  // 64-row tiles: sum ceil(cnt/64) <= 32+7, padded to 40

typedef __attribute__((ext_vector_type(8))) short bf16x8;
typedef __attribute__((ext_vector_type(4))) float f32x4;

__device__ inline unsigned short f2bf(float f) {
  __hip_bfloat16 b = __float2bfloat16(f);
  return *reinterpret_cast<unsigned short*>(&b);
}
__device__ inline unsigned int pack2(float lo, float hi) {
  return (unsigned int)f2bf(lo) | ((unsigned int)f2bf(hi) << 16);
}
__device__ inline float bf2f(unsigned short u) {
  unsigned int x = ((unsigned int)u) << 16;
  union { unsigned int i; float f; } c; c.i = x; return c.f;
}

// ---------------- Router: one wave per token ----------------
__global__ void router_kernel(const float* __restrict__ X, const float* __restrict__ Wr,
                              float* __restrict__ logits, float* __restrict__ idx_out,
                              int* __restrict__ expert, float* __restrict__ prob,
                              int* __restrict__ counts) {
  int wave = threadIdx.x >> 6, lane = threadIdx.x & 63;
  int t = blockIdx.x * 4 + wave;
  if (t >= T_TOKENS) return;
  const float* x = X + (size_t)t * H_DIM;
  float acc[E_NUM];
#pragma unroll
  for (int e = 0; e < E_NUM; ++e) acc[e] = 0.f;
  int h0 = lane * 12;
#pragma unroll
  for (int j = 0; j < 12; ++j) {
    float xv = x[h0 + j];
    const float4* wr = reinterpret_cast<const float4*>(Wr + (size_t)(h0 + j) * E_NUM);
    float4 w0 = wr[0], w1 = wr[1];
    acc[0] += xv * w0.x; acc[1] += xv * w0.y; acc[2] += xv * w0.z; acc[3] += xv * w0.w;
    acc[4] += xv * w1.x; acc[5] += xv * w1.y; acc[6] += xv * w1.z; acc[7] += xv * w1.w;
  }
#pragma unroll
  for (int e = 0; e < E_NUM; ++e) {
#pragma unroll
    for (int s = 32; s > 0; s >>= 1) acc[e] += __shfl_down(acc[e], s);
  }
  if (lane == 0) {
    float m = acc[0]; int am = 0;
#pragma unroll
    for (int e = 1; e < E_NUM; ++e) {
      if (acc[e] > m) { m = acc[e]; am = e; }  // strict > == jnp.argmax first-occurrence
    }
    float sum = 0.f;
#pragma unroll
    for (int e = 0; e < E_NUM; ++e) sum += __expf(acc[e] - m);
    float p = 1.f / sum;
#pragma unroll
    for (int e = 0; e < E_NUM; ++e) logits[(size_t)t * E_NUM + e] = acc[e];
    idx_out[t] = (float)am;
    expert[t] = am;
    prob[t] = p;
    atomicAdd(&counts[am], 1);
  }
}

// ------- Fused scan + scatter + slot table (one block) -------
__global__ void scan_scatter_kernel(const int* __restrict__ counts,
                                    const int* __restrict__ expert,
                                    int* __restrict__ offs, int* __restrict__ perm,
                                    int* __restrict__ mse, int* __restrict__ msm0) {
  __shared__ int so[E_NUM + 1];
  __shared__ int cur[E_NUM];
  int tid = threadIdx.x;
  if (tid == 0) {
    int s = 0;
    for (int e = 0; e < E_NUM; ++e) { so[e] = s; s += counts[e]; }
    so[E_NUM] = s;
    int ns = 0;
    for (int e = 0; e < E_NUM; ++e)
      for (int m0 = 0; m0 < counts[e]; m0 += 64) { mse[ns] = e; msm0[ns] = m0; ++ns; }
    for (; ns < MSLOTS; ++ns) { mse[ns] = -1; msm0[ns] = 0; }
  }
  if (tid < E_NUM) cur[tid] = 0;
  __syncthreads();
  if (tid < E_NUM + 1) offs[tid] = so[tid];
  for (int i = tid; i < T_TOKENS; i += blockDim.x) {
    int e = expert[i];
    int pos = atomicAdd(&cur[e], 1);
    perm[so[e] + pos] = i;
  }
}

// ------- Grouped GEMM: 64x64x64 tile, depth-2, 5 blocks/CU (LDS 32KB) -------
// C[m,n] (+k-chunk) = sum_{k in chunk} A[m,k] * W[e][k,n]. BM=BN=BK=64,
// chunk 768 (nt=12). 4 waves 2m x 2n, wavetile 32x32 (acc 2x2).
// Double-buffered 32KB LDS; single register staging set (depth-2) with
// __launch_bounds__(256,3): allocator stays at ~84 VGPR, NO SPILL (r8/r10
// lesson: min-waves >= 4 crushes VGPRs a tier and spills to scratch).
// Occupancy comes from LDS: 32KB -> 5 blocks/CU = 20 waves/CU.
// LDS rows 128B = 8 x 16B slots. A: linear source, write slot = sp^(row&7).
// B: 4n x 4k per thread, b64 writes at slot=(kg>>1)^h(r), half=kg&1,
// h(r) = (r&7)^((r>>3)&7). Fragment reads apply the same hashes.
// MODE 1: A = X f32 gathered via perm, out relu->bf16.
// MODE 0: A = bf16 linear (hbuf), out bf16 partials (split-K).
template <int MODE, int KT, int N, int KS>
__global__ __launch_bounds__(256, 3) void moe_gemm(
    const __hip_bfloat16* __restrict__ Abf, const float* __restrict__ Xf,
    const float* __restrict__ Wt,
    __hip_bfloat16* __restrict__ Cbf,
    const int* __restrict__ offs, const int* __restrict__ perm,
    const int* __restrict__ mse, const int* __restrict__ msm0) {
  constexpr int ABUF = 64 * 128;           // 8 KB
  constexpr int BUFSZ = ABUF + 64 * 128;   // 16 KB
  __shared__ __align__(16) char lds[2 * BUFSZ];  // 32 KB

  // ---- work decode with XCD-chunk swizzle (grid multiple of 8) ----
  const int nw = gridDim.x;
  const int cpx = nw >> 3;
  const int d = blockIdx.x;
  const int w = (d & 7) * cpx + (d >> 3);
  const int slot = w % MSLOTS;
  const int r_ = w / MSLOTS;
  const int ks = r_ % KS;
  const int nt_i = r_ / KS;
  const int e = mse[slot];
  if (e < 0) return;
  const int base = offs[e], cnt = offs[e + 1] - base;
  const int m0 = msm0[slot];
  const int rows = min(64, cnt - m0);
  const int n0 = nt_i * 64;
  const int koff = ks * 768;

  const int tid = threadIdx.x;
  const int lane = tid & 63, wv = tid >> 6;
  const int wr = wv >> 1, wc = wv & 1;     // 2m x 2n waves, wavetile 32x32
  const int lr = lane & 15, lg = lane >> 4;

  // ---- A staging: row=tid>>2, two 16B slots; linear source, swizzled write ----
  const int arow = tid >> 2, sp0 = (tid & 3) * 2, sp1 = sp0 + 1;
  const int arl = min(arow, rows - 1);
  const float* Ax0 = nullptr;
  const __hip_bfloat16* Ab0 = nullptr;
  if constexpr (MODE) {
    Ax0 = Xf + (size_t)perm[base + m0 + arl] * KT + sp0 * 8;
  } else {
    Ab0 = Abf + (size_t)(base + m0 + arl) * KT + koff + sp0 * 8;
  }
  const int a_woff0 = arow * 128 + ((sp0 ^ (arow & 7)) << 4);
  const int a_woff1 = arow * 128 + ((sp1 ^ (arow & 7)) << 4);

  // ---- B staging: 4 n-cols x 4 k-rows per thread, f32x4 loads, b64 writes ----
  const int n4 = (tid & 15) * 4;
  const int kg = tid >> 4;                 // 0..15, k = kg*4 .. kg*4+3
  const float* Bp = Wt + (size_t)e * KT * N + (size_t)(koff + kg * 4) * N + n0 + n4;
  int b_woff[4];
#pragma unroll
  for (int cc = 0; cc < 4; ++cc) {
    int rr = n4 + cc;
    int h_ = (rr & 7) ^ ((rr >> 3) & 7);
    b_woff[cc] = ABUF + rr * 128 + ((((kg >> 1) ^ h_) << 4) | ((kg & 1) << 3));
  }

  // ---- fragment LDS offsets ----
  int aof[2][2], bof[2][2];
#pragma unroll
  for (int k2 = 0; k2 < 2; ++k2) {
#pragma unroll
    for (int mi = 0; mi < 2; ++mi) {
      int ar = wr * 32 + mi * 16 + lr;
      aof[k2][mi] = ar * 128 + (((k2 * 4 + lg) ^ (ar & 7)) << 4);
    }
#pragma unroll
    for (int ni = 0; ni < 2; ++ni) {
      int br = wc * 32 + ni * 16 + lr;
      bof[k2][ni] = ABUF + br * 128 +
                    (((k2 * 4 + lg) ^ (br & 7) ^ ((br >> 3) & 7)) << 4);
    }
  }

  f32x4 acc[2][2];
#pragma unroll
  for (int i = 0; i < 2; ++i)
#pragma unroll
    for (int j = 0; j < 2; ++j) acc[i][j] = (f32x4){0.f, 0.f, 0.f, 0.f};

  // single register staging set (depth-2)
  f32x4 af[4];
  int4 aq[2];
  f32x4 bq[4];

#define LOADT(TT) {                                                             \
    if constexpr (MODE) {                                                       \
      af[0] = *reinterpret_cast<const f32x4*>(Ax0 + (TT) * 64);                 \
      af[1] = *reinterpret_cast<const f32x4*>(Ax0 + (TT) * 64 + 4);             \
      af[2] = *reinterpret_cast<const f32x4*>(Ax0 + (TT) * 64 + 8);             \
      af[3] = *reinterpret_cast<const f32x4*>(Ax0 + (TT) * 64 + 12);            \
    } else {                                                                    \
      aq[0] = *reinterpret_cast<const int4*>(Ab0 + (TT) * 64);                  \
      aq[1] = *reinterpret_cast<const int4*>(Ab0 + (TT) * 64 + 8);              \
    }                                                                           \
    _Pragma("unroll")                                                           \
    for (int j = 0; j < 4; ++j)                                                 \
      bq[j] = *reinterpret_cast<const f32x4*>(Bp + (size_t)((TT) * 64 + j) * N); \
  }

#define WRITET(WB) {                                                            \
    char* wb_ = (WB);                                                           \
    if constexpr (MODE) {                                                       \
      int4 ua_;                                                                 \
      ua_.x = (int)pack2(af[0][0], af[0][1]);                                   \
      ua_.y = (int)pack2(af[0][2], af[0][3]);                                   \
      ua_.z = (int)pack2(af[1][0], af[1][1]);                                   \
      ua_.w = (int)pack2(af[1][2], af[1][3]);                                   \
      *reinterpret_cast<int4*>(wb_ + a_woff0) = ua_;                            \
      ua_.x = (int)pack2(af[2][0], af[2][1]);                                   \
      ua_.y = (int)pack2(af[2][2], af[2][3]);                                   \
      ua_.z = (int)pack2(af[3][0], af[3][1]);                                   \
      ua_.w = (int)pack2(af[3][2], af[3][3]);                                   \
      *reinterpret_cast<int4*>(wb_ + a_woff1) = ua_;                            \
    } else {                                                                    \
      *reinterpret_cast<int4*>(wb_ + a_woff0) = aq[0];                          \
      *reinterpret_cast<int4*>(wb_ + a_woff1) = aq[1];                          \
    }                                                                           \
    _Pragma("unroll")                                                           \
    for (int cc = 0; cc < 4; ++cc) {                                            \
      int2 u_;                                                                  \
      u_.x = (int)pack2(bq[0][cc], bq[1][cc]);                                  \
      u_.y = (int)pack2(bq[2][cc], bq[3][cc]);                                  \
      *reinterpret_cast<int2*>(wb_ + b_woff[cc]) = u_;                          \
    }                                                                           \
  }

#define MFMA_STEP(RB) {                                                         \
    const char* rb_ = (RB);                                                     \
    _Pragma("unroll")                                                           \
    for (int k2 = 0; k2 < 2; ++k2) {                                            \
      bf16x8 av0 = *reinterpret_cast<const bf16x8*>(rb_ + aof[k2][0]);          \
      bf16x8 av1 = *reinterpret_cast<const bf16x8*>(rb_ + aof[k2][1]);          \
      bf16x8 bv0 = *reinterpret_cast<const bf16x8*>(rb_ + bof[k2][0]);          \
      bf16x8 bv1 = *reinterpret_cast<const bf16x8*>(rb_ + bof[k2][1]);          \
      acc[0][0] = __builtin_amdgcn_mfma_f32_16x16x32_bf16(av0, bv0, acc[0][0], 0, 0, 0); \
      acc[0][1] = __builtin_amdgcn_mfma_f32_16x16x32_bf16(av0, bv1, acc[0][1], 0, 0, 0); \
      acc[1][0] = __builtin_amdgcn_mfma_f32_16x16x32_bf16(av1, bv0, acc[1][0], 0, 0, 0); \
      acc[1][1] = __builtin_amdgcn_mfma_f32_16x16x32_bf16(av1, bv1, acc[1][1], 0, 0, 0); \
    }                                                                           \
  }

#define SYNCB() {                                                               \
    asm volatile("s_waitcnt lgkmcnt(0)" ::: "memory");                          \
    __builtin_amdgcn_s_barrier();                                               \
    __builtin_amdgcn_sched_barrier(0);                                          \
  }

  char* const buf0 = lds;
  char* const buf1 = lds + BUFSZ;

  // prologue: tile0 -> buf0; tile1 loads in flight
  LOADT(0);
  WRITET(buf0);
  LOADT(1);
  SYNCB();

  // branch-free body: step t reads buf[t&1], writes tile t+1, loads t+2
#pragma unroll 1
  for (int t0 = 0; t0 < 10; t0 += 2) {
    MFMA_STEP(buf0); WRITET(buf1); LOADT(t0 + 2); SYNCB();
    MFMA_STEP(buf1); WRITET(buf0); LOADT(t0 + 3); SYNCB();
  }
  MFMA_STEP(buf0); WRITET(buf1); SYNCB();   // t=10, tile 11 written
  MFMA_STEP(buf1);                          // t=11
#undef LOADT
#undef WRITET
#undef MFMA_STEP
#undef SYNCB

  // ---- epilogue: C/D frag row=(lane>>4)*4+reg, col=lane&15 ----
#pragma unroll
  for (int mi = 0; mi < 2; ++mi) {
#pragma unroll
    for (int r = 0; r < 4; ++r) {
      int row = wr * 32 + mi * 16 + lg * 4 + r;
      if (row < rows) {
        if (MODE) {
          __hip_bfloat16* dst = Cbf + (size_t)(base + m0 + row) * N + n0 + wc * 32 + lr;
#pragma unroll
          for (int ni = 0; ni < 2; ++ni) {
            float v = acc[mi][ni][r];
            dst[ni * 16] = __float2bfloat16(v > 0.f ? v : 0.f);
          }
        } else {
          __hip_bfloat16* dst =
              Cbf + ((size_t)ks * T_TOKENS + base + m0 + row) * N + n0 + wc * 32 + lr;
#pragma unroll
          for (int ni = 0; ni < 2; ++ni)
            dst[ni * 16] = __float2bfloat16(acc[mi][ni][r]);
        }
      }
    }
  }
}

// -------- Split-K reduce: sum 4 bf16 partials, scale by prob, scatter --------
__global__ void reduce_kernel(const __hip_bfloat16* __restrict__ pc,
                              const int* __restrict__ perm,
                              const float* __restrict__ prob, float* __restrict__ out) {
  int idx = blockIdx.x * 256 + threadIdx.x;      // 2048 * 192
  int g = idx / (H_DIM / 4);
  int c4 = (idx - g * (H_DIM / 4)) * 4;
  int token = perm[g];
  float p = prob[token];
  float s0 = 0.f, s1 = 0.f, s2 = 0.f, s3 = 0.f;
#pragma unroll
  for (int ks = 0; ks < 4; ++ks) {
    ushort4 u = *reinterpret_cast<const ushort4*>(
        pc + ((size_t)ks * T_TOKENS + g) * H_DIM + c4);
    s0 += bf2f(u.x); s1 += bf2f(u.y); s2 += bf2f(u.z); s3 += bf2f(u.w);
  }
  f32x4 v = (f32x4){s0 * p, s1 * p, s2 * p, s3 * p};
  *reinterpret_cast<f32x4*>(out + (size_t)token * H_DIM + c4) = v;
}

extern "C" void kernel_launch(void* const* d_in, const int* in_sizes, int n_in,
                              void* d_out, int out_size, void* d_ws, size_t ws_size,
                              hipStream_t stream) {
  const float* X = (const float*)d_in[0];
  const float* Wr = (const float*)d_in[1];
  const float* W1 = (const float*)d_in[2];
  const float* W2 = (const float*)d_in[3];

  float* out_states = (float*)d_out;
  float* out_logits = out_states + (size_t)T_TOKENS * H_DIM;
  float* out_index = out_logits + (size_t)T_TOKENS * E_NUM;

  char* ws = (char*)d_ws;
  int* counts = (int*)(ws + 0);        // 8 ints
  int* offs = (int*)(ws + 64);         // 9 ints
  int* expert = (int*)(ws + 128);      // 2048 ints
  float* prob = (float*)(ws + 8320);   // 2048 f32
  int* perm = (int*)(ws + 16512);      // 2048 ints
  int* mse = (int*)(ws + 24704);       // 40 ints
  int* msm0 = (int*)(ws + 24896);      // 40 ints
  __hip_bfloat16* hbuf = (__hip_bfloat16*)(ws + 3171456);   // 2048*3072 bf16
  __hip_bfloat16* pc = (__hip_bfloat16*)(ws + 15754368);    // 4*2048*768 bf16

  hipMemsetAsync(d_ws, 0, 64, stream);  // zero counts

  router_kernel<<<T_TOKENS / 4, 256, 0, stream>>>(X, Wr, out_logits, out_index, expert, prob, counts);
  scan_scatter_kernel<<<1, 1024, 0, stream>>>(counts, expert, offs, perm, mse, msm0);

  // h = relu(gather(X) @ W1[e]) : K=768, N=3072 -> 48 x 40 = 1920 blocks
  moe_gemm<1, H_DIM, F_DIM, 1><<<(F_DIM / 64) * MSLOTS, 256, 0, stream>>>(
      nullptr, X, W1, hbuf, offs, perm, mse, msm0);
  // partial y_ks = h @ W2[e][ks-chunk] : 4 chunks of 768 -> 12 x 4 x 40 = 1920 blocks
  moe_gemm<0, F_DIM, H_DIM, 4><<<(H_DIM / 64) * 4 * MSLOTS, 256, 0, stream>>>(
      hbuf, nullptr, W2, pc, offs, perm, mse, msm0);
  // out[token] = prob * sum_ks pc[ks][g]
  reduce_kernel<<<(T_TOKENS * (H_DIM / 4)) / 256, 256, 0, stream>>>(pc, perm, prob, out_states);
}

// Round 12
// 117.984 us; speedup vs baseline: 1.5744x; 1.3339x over previous
//
#include <hip/hip_runtime.h>
#include <hip/hip_bf16.h>

// Switch MoE (top-1), B=2 S=1024 H=768 F=3072 E=8 on MI355X.
// Outputs concat in d_out: next_states[2048*768] f32, router_logits[2048*8] f32,
// expert_index[2048] written as float values.

#define T_TOKENS 2048
#define H_DIM 768
#define F_DIM 3072
#define E_NUM 8
#define MSLOTS 40  // 64-row tiles: sum ceil(cnt/64) <= 32+7, padded to 40

typedef __attribute__((ext_vector_type(8))) short bf16x8;
typedef __attribute__((ext_vector_type(4))) float f32x4;

__device__ inline unsigned short f2bf(float f) {
  __hip_bfloat16 b = __float2bfloat16(f);
  return *reinterpret_cast<unsigned short*>(&b);
}
__device__ inline unsigned int pack2(float lo, float hi) {
  return (unsigned int)f2bf(lo) | ((unsigned int)f2bf(hi) << 16);
}
__device__ inline float bf2f(unsigned short u) {
  unsigned int x = ((unsigned int)u) << 16;
  union { unsigned int i; float f; } c; c.i = x; return c.f;
}

// Async global->LDS, 16B per lane. LDS dest must be wave-uniform base
// (HW writes lane i at base + i*16); global source is per-lane.
typedef const __attribute__((address_space(1))) void* gas_ptr;
typedef __attribute__((address_space(3))) void* las_ptr;
__device__ inline void gload16(const void* g, void* l) {
  __builtin_amdgcn_global_load_lds((gas_ptr)g, (las_ptr)l, 16, 0, 0);
}

// ---------------- Router: one wave per token ----------------
__global__ void router_kernel(const float* __restrict__ X, const float* __restrict__ Wr,
                              float* __restrict__ logits, float* __restrict__ idx_out,
                              int* __restrict__ expert, float* __restrict__ prob,
                              int* __restrict__ counts) {
  int wave = threadIdx.x >> 6, lane = threadIdx.x & 63;
  int t = blockIdx.x * 4 + wave;
  if (t >= T_TOKENS) return;
  const float* x = X + (size_t)t * H_DIM;
  float acc[E_NUM];
#pragma unroll
  for (int e = 0; e < E_NUM; ++e) acc[e] = 0.f;
  int h0 = lane * 12;
#pragma unroll
  for (int j = 0; j < 12; ++j) {
    float xv = x[h0 + j];
    const float4* wr = reinterpret_cast<const float4*>(Wr + (size_t)(h0 + j) * E_NUM);
    float4 w0 = wr[0], w1 = wr[1];
    acc[0] += xv * w0.x; acc[1] += xv * w0.y; acc[2] += xv * w0.z; acc[3] += xv * w0.w;
    acc[4] += xv * w1.x; acc[5] += xv * w1.y; acc[6] += xv * w1.z; acc[7] += xv * w1.w;
  }
#pragma unroll
  for (int e = 0; e < E_NUM; ++e) {
#pragma unroll
    for (int s = 32; s > 0; s >>= 1) acc[e] += __shfl_down(acc[e], s);
  }
  if (lane == 0) {
    float m = acc[0]; int am = 0;
#pragma unroll
    for (int e = 1; e < E_NUM; ++e) {
      if (acc[e] > m) { m = acc[e]; am = e; }  // strict > == jnp.argmax first-occurrence
    }
    float sum = 0.f;
#pragma unroll
    for (int e = 0; e < E_NUM; ++e) sum += __expf(acc[e] - m);
    float p = 1.f / sum;
#pragma unroll
    for (int e = 0; e < E_NUM; ++e) logits[(size_t)t * E_NUM + e] = acc[e];
    idx_out[t] = (float)am;
    expert[t] = am;
    prob[t] = p;
    atomicAdd(&counts[am], 1);
  }
}

// ------- Fused scan + scatter + slot table (one block) -------
__global__ void scan_scatter_kernel(const int* __restrict__ counts,
                                    const int* __restrict__ expert,
                                    int* __restrict__ offs, int* __restrict__ perm,
                                    int* __restrict__ mse, int* __restrict__ msm0) {
  __shared__ int so[E_NUM + 1];
  __shared__ int cur[E_NUM];
  int tid = threadIdx.x;
  if (tid == 0) {
    int s = 0;
    for (int e = 0; e < E_NUM; ++e) { so[e] = s; s += counts[e]; }
    so[E_NUM] = s;
    int ns = 0;
    for (int e = 0; e < E_NUM; ++e)
      for (int m0 = 0; m0 < counts[e]; m0 += 64) { mse[ns] = e; msm0[ns] = m0; ++ns; }
    for (; ns < MSLOTS; ++ns) { mse[ns] = -1; msm0[ns] = 0; }
  }
  if (tid < E_NUM) cur[tid] = 0;
  __syncthreads();
  if (tid < E_NUM + 1) offs[tid] = so[tid];
  for (int i = tid; i < T_TOKENS; i += blockDim.x) {
    int e = expert[i];
    int pos = atomicAdd(&cur[e], 1);
    perm[so[e] + pos] = i;
  }
}

// ---------------- Gather X rows -> contiguous bf16 ----------------
__global__ void gather_kernel(const float* __restrict__ X, const int* __restrict__ perm,
                              __hip_bfloat16* __restrict__ xg) {
  int wave = threadIdx.x >> 6, lane = threadIdx.x & 63;
  int g = blockIdx.x * 4 + wave;
  if (g >= T_TOKENS) return;
  int token = perm[g];
  const float4* src = reinterpret_cast<const float4*>(X + (size_t)token * H_DIM + lane * 12);
  __hip_bfloat16* dst = xg + (size_t)g * H_DIM + lane * 12;
#pragma unroll
  for (int i = 0; i < 3; ++i) {
    float4 v = src[i];
    ushort4 u;
    u.x = f2bf(v.x); u.y = f2bf(v.y); u.z = f2bf(v.z); u.w = f2bf(v.w);
    *reinterpret_cast<ushort4*>(dst + i * 4) = u;
  }
}

// ------- Grouped GEMM: r7 geometry + global_load_lds A-staging -------
// C[m,n] (+k-chunk) = sum_{k in chunk} A[m,k] * W[e][k,n]. BM=64, BN=128,
// BK=64, chunk 768 (nt=12). 4 waves 2m x 2n, wavetile 32x64 (acc 2x4).
// Double-buffered 48KB LDS, __launch_bounds__(256,3) (proven no-spill tier).
// A (bf16): async global_load_lds, swizzle folded into per-lane SOURCE addr,
//   LDS dest linear. A-gloads for tile t+1 issue in step t into the free
//   buffer; counted vmcnt(8) before the barrier drains A-gloads while the
//   8 B prefetch loads stay in flight.
// B (f32 [K][N]): reg-staged 4n x 8k per thread, packed to bf16, b128 writes
//   at hashed slots. LDS rows 128B = 8 x 16B slots; hash h(r)=(r&7)^((r>>3)&7).
// MODE 1: out = relu -> bf16 (hbuf). MODE 0: out = bf16 partials (split-K).
template <int MODE, int KT, int N, int KS>
__global__ __launch_bounds__(256, 3) void moe_gemm(
    const __hip_bfloat16* __restrict__ Abf, const float* __restrict__ Wt,
    __hip_bfloat16* __restrict__ Cbf,
    const int* __restrict__ offs, const int* __restrict__ mse,
    const int* __restrict__ msm0) {
  constexpr int ABUF = 64 * 128;           // 8 KB
  constexpr int BUFSZ = ABUF + 128 * 128;  // 24 KB
  __shared__ __align__(16) char lds[2 * BUFSZ];  // 48 KB

  // ---- work decode with XCD-chunk swizzle (grid multiple of 8) ----
  const int nw = gridDim.x;
  const int cpx = nw >> 3;
  const int d = blockIdx.x;
  const int w = (d & 7) * cpx + (d >> 3);
  const int slot = w % MSLOTS;
  const int r_ = w / MSLOTS;
  const int ks = r_ % KS;
  const int nt_i = r_ / KS;
  const int e = mse[slot];
  if (e < 0) return;
  const int base = offs[e], cnt = offs[e + 1] - base;
  const int m0 = msm0[slot];
  const int rows = min(64, cnt - m0);
  const int n0 = nt_i * 128;
  const int koff = ks * 768;

  const int tid = threadIdx.x;
  const int lane = tid & 63, wv = tid >> 6;
  const int wr = wv >> 1, wc = wv & 1;     // 2m x 2n waves, wavetile 32x64
  const int lr = lane & 15, lg = lane >> 4;

  // ---- A async staging: wave wv covers rows wv*8..wv*8+7 (and +32) ----
  // lane l -> row = wv*8 + (l>>3), dest slot = l&7; source k-slot = (l&7)^(row&7)
  const int arow0 = wv * 8 + (lane >> 3);
  const int arow1 = arow0 + 32;
  const int aslot = (lane & 7) ^ (arow0 & 7);  // (arow1&7)==(arow0&7)
  const __hip_bfloat16* agp0 =
      Abf + (size_t)(base + m0 + min(arow0, rows - 1)) * KT + koff + aslot * 8;
  const __hip_bfloat16* agp1 =
      Abf + (size_t)(base + m0 + min(arow1, rows - 1)) * KT + koff + aslot * 8;
  const int a_ldst0 = wv * 1024;           // wave-uniform LDS byte offsets
  const int a_ldst1 = 4096 + wv * 1024;

  // ---- B staging: 4 n-cols x 8 k-rows per thread, f32x4 loads ----
  const int n4 = (tid & 31) * 4;
  const int s_ = tid >> 5;                 // 0..7, k = 8*s_
  const float* Bp = Wt + (size_t)e * KT * N + (size_t)(koff + s_ * 8) * N + n0 + n4;
  int b_woff[4];
#pragma unroll
  for (int cc = 0; cc < 4; ++cc) {
    int rr = n4 + cc;
    int h_ = (rr & 7) ^ ((rr >> 3) & 7);
    b_woff[cc] = ABUF + rr * 128 + ((s_ ^ h_) << 4);
  }

  // ---- fragment LDS offsets ----
  int aof[2][2], bof[2][4];
#pragma unroll
  for (int k2 = 0; k2 < 2; ++k2) {
#pragma unroll
    for (int mi = 0; mi < 2; ++mi) {
      int ar = wr * 32 + mi * 16 + lr;
      aof[k2][mi] = ar * 128 + (((k2 * 4 + lg) ^ (ar & 7)) << 4);
    }
#pragma unroll
    for (int ni = 0; ni < 4; ++ni) {
      int br = wc * 64 + ni * 16 + lr;
      bof[k2][ni] = ABUF + br * 128 +
                    (((k2 * 4 + lg) ^ (br & 7) ^ ((br >> 3) & 7)) << 4);
    }
  }

  f32x4 acc[2][4];
#pragma unroll
  for (int i = 0; i < 2; ++i)
#pragma unroll
    for (int j = 0; j < 4; ++j) acc[i][j] = (f32x4){0.f, 0.f, 0.f, 0.f};

  f32x4 bq[8];

#define AGL(TT, WB) {                                                           \
    gload16(agp0 + (TT) * 64, (WB) + a_ldst0);                                  \
    gload16(agp1 + (TT) * 64, (WB) + a_ldst1);                                  \
  }

#define LOADB(TT) {                                                             \
    _Pragma("unroll")                                                           \
    for (int r = 0; r < 8; ++r)                                                 \
      bq[r] = *reinterpret_cast<const f32x4*>(Bp + (size_t)((TT) * 64 + r) * N);\
  }

#define WRITEB(WB) {                                                            \
    char* wb_ = (WB);                                                           \
    _Pragma("unroll")                                                           \
    for (int cc = 0; cc < 4; ++cc) {                                            \
      int4 u_;                                                                  \
      u_.x = (int)pack2(bq[0][cc], bq[1][cc]);                                  \
      u_.y = (int)pack2(bq[2][cc], bq[3][cc]);                                  \
      u_.z = (int)pack2(bq[4][cc], bq[5][cc]);                                  \
      u_.w = (int)pack2(bq[6][cc], bq[7][cc]);                                  \
      *reinterpret_cast<int4*>(wb_ + b_woff[cc]) = u_;                          \
    }                                                                           \
  }

#define MFMA_STEP(RB) {                                                         \
    const char* rb_ = (RB);                                                     \
    _Pragma("unroll")                                                           \
    for (int k2 = 0; k2 < 2; ++k2) {                                            \
      bf16x8 av0 = *reinterpret_cast<const bf16x8*>(rb_ + aof[k2][0]);          \
      bf16x8 av1 = *reinterpret_cast<const bf16x8*>(rb_ + aof[k2][1]);          \
      _Pragma("unroll")                                                         \
      for (int ni = 0; ni < 4; ++ni) {                                          \
        bf16x8 bv = *reinterpret_cast<const bf16x8*>(rb_ + bof[k2][ni]);        \
        acc[0][ni] = __builtin_amdgcn_mfma_f32_16x16x32_bf16(av0, bv, acc[0][ni], 0, 0, 0); \
        acc[1][ni] = __builtin_amdgcn_mfma_f32_16x16x32_bf16(av1, bv, acc[1][ni], 0, 0, 0); \
      }                                                                         \
    }                                                                           \
  }

  // full-step sync: keep the 8 B-prefetch loads in flight, drain A-gloads
#define SYNCF() {                                                               \
    asm volatile("s_waitcnt vmcnt(8)" ::: "memory");                            \
    asm volatile("s_waitcnt lgkmcnt(0)" ::: "memory");                          \
    __builtin_amdgcn_s_barrier();                                               \
    __builtin_amdgcn_sched_barrier(0);                                          \
  }
  // drain sync (tail): everything done
#define SYNCD() {                                                               \
    asm volatile("s_waitcnt vmcnt(0)" ::: "memory");                            \
    asm volatile("s_waitcnt lgkmcnt(0)" ::: "memory");                          \
    __builtin_amdgcn_s_barrier();                                               \
    __builtin_amdgcn_sched_barrier(0);                                          \
  }

  char* const buf0 = lds;
  char* const buf1 = lds + BUFSZ;

  // prologue: tile0 fully staged; B(1) in flight
  AGL(0, buf0);
  LOADB(0);
  WRITEB(buf0);   // compiler waits B(0) regs -> also drains A-gloads(0)
  LOADB(1);
  SYNCF();        // outstanding: B(1)=8 -> no stall

  // step t: MFMA buf[t&1]; A-gload tile t+1 -> free buffer; write B(t+1);
  // issue B(t+2); counted-vmcnt barrier. nt=12: t=0..9 branch-free.
#pragma unroll 1
  for (int t0 = 0; t0 < 10; t0 += 2) {
    MFMA_STEP(buf0); AGL(t0 + 1, buf1); WRITEB(buf1); LOADB(t0 + 2); SYNCF();
    MFMA_STEP(buf1); AGL(t0 + 2, buf0); WRITEB(buf0); LOADB(t0 + 3); SYNCF();
  }
  MFMA_STEP(buf0); AGL(11, buf1); WRITEB(buf1); SYNCD();  // t=10
  MFMA_STEP(buf1);                                        // t=11
#undef AGL
#undef LOADB
#undef WRITEB
#undef MFMA_STEP
#undef SYNCF
#undef SYNCD

  // ---- epilogue: C/D frag row=(lane>>4)*4+reg, col=lane&15 ----
#pragma unroll
  for (int mi = 0; mi < 2; ++mi) {
#pragma unroll
    for (int r = 0; r < 4; ++r) {
      int row = wr * 32 + mi * 16 + lg * 4 + r;
      if (row < rows) {
        if (MODE) {
          __hip_bfloat16* dst = Cbf + (size_t)(base + m0 + row) * N + n0 + wc * 64 + lr;
#pragma unroll
          for (int ni = 0; ni < 4; ++ni) {
            float v = acc[mi][ni][r];
            dst[ni * 16] = __float2bfloat16(v > 0.f ? v : 0.f);
          }
        } else {
          __hip_bfloat16* dst =
              Cbf + ((size_t)ks * T_TOKENS + base + m0 + row) * N + n0 + wc * 64 + lr;
#pragma unroll
          for (int ni = 0; ni < 4; ++ni)
            dst[ni * 16] = __float2bfloat16(acc[mi][ni][r]);
        }
      }
    }
  }
}

// -------- Split-K reduce: sum 4 bf16 partials, scale by prob, scatter --------
__global__ void reduce_kernel(const __hip_bfloat16* __restrict__ pc,
                              const int* __restrict__ perm,
                              const float* __restrict__ prob, float* __restrict__ out) {
  int idx = blockIdx.x * 256 + threadIdx.x;      // 2048 * 192
  int g = idx / (H_DIM / 4);
  int c4 = (idx - g * (H_DIM / 4)) * 4;
  int token = perm[g];
  float p = prob[token];
  float s0 = 0.f, s1 = 0.f, s2 = 0.f, s3 = 0.f;
#pragma unroll
  for (int ks = 0; ks < 4; ++ks) {
    ushort4 u = *reinterpret_cast<const ushort4*>(
        pc + ((size_t)ks * T_TOKENS + g) * H_DIM + c4);
    s0 += bf2f(u.x); s1 += bf2f(u.y); s2 += bf2f(u.z); s3 += bf2f(u.w);
  }
  f32x4 v = (f32x4){s0 * p, s1 * p, s2 * p, s3 * p};
  *reinterpret_cast<f32x4*>(out + (size_t)token * H_DIM + c4) = v;
}

extern "C" void kernel_launch(void* const* d_in, const int* in_sizes, int n_in,
                              void* d_out, int out_size, void* d_ws, size_t ws_size,
                              hipStream_t stream) {
  const float* X = (const float*)d_in[0];
  const float* Wr = (const float*)d_in[1];
  const float* W1 = (const float*)d_in[2];
  const float* W2 = (const float*)d_in[3];

  float* out_states = (float*)d_out;
  float* out_logits = out_states + (size_t)T_TOKENS * H_DIM;
  float* out_index = out_logits + (size_t)T_TOKENS * E_NUM;

  char* ws = (char*)d_ws;
  int* counts = (int*)(ws + 0);        // 8 ints
  int* offs = (int*)(ws + 64);         // 9 ints
  int* expert = (int*)(ws + 128);      // 2048 ints
  float* prob = (float*)(ws + 8320);   // 2048 f32
  int* perm = (int*)(ws + 16512);      // 2048 ints
  int* mse = (int*)(ws + 24704);       // 40 ints
  int* msm0 = (int*)(ws + 24896);      // 40 ints
  __hip_bfloat16* xg = (__hip_bfloat16*)(ws + 25088);       // 2048*768 bf16
  __hip_bfloat16* hbuf = (__hip_bfloat16*)(ws + 3171456);   // 2048*3072 bf16
  __hip_bfloat16* pc = (__hip_bfloat16*)(ws + 15754368);    // 4*2048*768 bf16

  hipMemsetAsync(d_ws, 0, 64, stream);  // zero counts

  router_kernel<<<T_TOKENS / 4, 256, 0, stream>>>(X, Wr, out_logits, out_index, expert, prob, counts);
  scan_scatter_kernel<<<1, 1024, 0, stream>>>(counts, expert, offs, perm, mse, msm0);
  gather_kernel<<<T_TOKENS / 4, 256, 0, stream>>>(X, perm, xg);

  // h = relu(xg @ W1[e]) : K=768, N=3072 -> 24 x 40 = 960 blocks
  moe_gemm<1, H_DIM, F_DIM, 1><<<(F_DIM / 128) * MSLOTS, 256, 0, stream>>>(
      xg, W1, hbuf, offs, mse, msm0);
  // partial y_ks = h @ W2[e][ks-chunk] : 4 chunks of 768 -> 6 x 4 x 40 = 960 blocks
  moe_gemm<0, F_DIM, H_DIM, 4><<<(H_DIM / 128) * 4 * MSLOTS, 256, 0, stream>>>(
      hbuf, W2, pc, offs, mse, msm0);
  // out[token] = prob * sum_ks pc[ks][g]
  reduce_kernel<<<(T_TOKENS * (H_DIM / 4)) / 256, 256, 0, stream>>>(pc, perm, prob, out_states);
}